// Round 8
// baseline (391.859 us; speedup 1.0000x reference)
//
#include <hip/hip_runtime.h>
#include <hip/hip_bf16.h>
#include <stdint.h>

#define SEQ 2048
#define DDIM 768
#define KF 24
#define NKV 48
#define NCHUNK 216   // 3 et2 * 72 (p,jj) chunks

typedef unsigned short ushort_t;
typedef __attribute__((ext_vector_type(8))) short short8;
typedef __attribute__((ext_vector_type(4))) float f32x4;

typedef __attribute__((address_space(3))) uint32_t lds_u32;
typedef __attribute__((address_space(1))) uint32_t glb_u32;

__device__ __forceinline__ unsigned short f2bf(float f) {
    union { float f; uint32_t u; } v; v.f = f;
    uint32_t u = v.u;
    return (unsigned short)((u + 0x7fff + ((u >> 16) & 1)) >> 16);
}

// Image layout for a [128 rows][64 k] bf16 slab (16 KB), XOR-swizzled:
//   idx(row,k) = row*64 + (((k>>3) ^ (row&7))<<3) + (k&7)

// ---------------- prep: pack x ----------------
__global__ void k_pack_x(const float* __restrict__ x, ushort_t* __restrict__ xpk) {
    int b = blockIdx.x;            // tt*12 + ks
    int tt = b / 12, ks = b % 12;
    int tid = threadIdx.x;
    ushort_t* dst = xpk + (size_t)b * 8192;
    const float* src = x + (size_t)tt * 128 * DDIM + ks * 64;
#pragma unroll
    for (int p = 0; p < 4; ++p) {
        int s = p * 256 + tid;
        int row = s >> 3, sl = s & 7;
        const float* rp = src + (size_t)row * DDIM + sl * 8;
        float4 a = *(const float4*)rp;
        float4 c = *(const float4*)(rp + 4);
        ushort_t v[8] = {f2bf(a.x), f2bf(a.y), f2bf(a.z), f2bf(a.w),
                         f2bf(c.x), f2bf(c.y), f2bf(c.z), f2bf(c.w)};
        *(uint4*)(dst + row * 64 + ((sl ^ (row & 7)) << 3)) = *(uint4*)v;
    }
}

// ---------------- prep: pack M transposed ----------------
__global__ void k_pack_M(const float* __restrict__ Mp, const float* __restrict__ Mm,
                         ushort_t* __restrict__ Mpk) {
    __shared__ ushort_t lt[128 * 66];
    int b = blockIdx.x;            // (kv*6 + et)*12 + ks
    int kv = b / 72; int rem = b % 72; int et = rem / 12, ks = rem % 12;
    const float* src = ((kv < KF) ? Mp + (size_t)kv * DDIM * DDIM
                                  : Mm + (size_t)(kv - KF) * DDIM * DDIM)
                       + (size_t)(ks * 64) * DDIM + et * 128;
    int tid = threadIdx.x;
#pragma unroll
    for (int p = 0; p < 32; ++p) {
        int lin = p * 256 + tid;
        int d = lin >> 7, e = lin & 127;
        lt[e * 66 + d] = f2bf(src[(size_t)d * DDIM + e]);
    }
    __syncthreads();
    ushort_t* dst = Mpk + (size_t)b * 8192;
#pragma unroll
    for (int p = 0; p < 4; ++p) {
        int s = p * 256 + tid; int row = s >> 3, sl = s & 7;
        ushort_t v[8];
#pragma unroll
        for (int j = 0; j < 8; ++j) v[j] = lt[row * 66 + sl * 8 + j];
        *(uint4*)(dst + row * 64 + ((sl ^ (row & 7)) << 3)) = *(uint4*)v;
    }
}

// ---------------- prep: build Toeplitz blocks (17 lag slots, slot 0 = zeros) ----------------
__global__ void k_build_T(const float* __restrict__ phi, ushort_t* __restrict__ Tpk) {
    __shared__ float phiL[256];
    int b = blockIdx.x;            // kv*17 + slot
    int kv = b / 17, slot = b % 17;
    int dm = slot - 1;             // lag block; dm = -1 -> all zero
    int k = kv % KF; bool neg = kv >= KF;
    int tid = threadIdx.x;
    int tau = 128 * dm - 127 + tid;
    float v = 0.f;
    if (tid < 255 && tau >= 0 && tau < SEQ) {
        v = phi[(size_t)tau * KF + k];
        if (neg && (tau & 1)) v = -v;
    }
    phiL[tid] = v;
    __syncthreads();
    ushort_t* dst = Tpk + (size_t)b * 2 * 8192;
#pragma unroll
    for (int h = 0; h < 2; ++h) {
#pragma unroll
        for (int p = 0; p < 4; ++p) {
            int s = p * 256 + tid; int row = s >> 3, sl = s & 7;
            ushort_t v8[8];
#pragma unroll
            for (int j = 0; j < 8; ++j) {
                int col = h * 64 + sl * 8 + j;
                v8[j] = f2bf(phiL[row - col + 127]);
            }
            *(uint4*)(dst + h * 8192 + row * 64 + ((sl ^ (row & 7)) << 3)) = *(uint4*)v8;
        }
    }
}

// ---------------- shared fragment-read helpers (gemm_A) ----------------

__device__ __forceinline__ void read_frags(const ushort_t* As, const ushort_t* Bs,
                                           int lane, int wm, int wn, int kk,
                                           short8 av[4], short8 bv[4]) {
    int slot = kk * 4 + (lane >> 4);
#pragma unroll
    for (int m = 0; m < 4; ++m) {
        int row = wm * 64 + m * 16 + (lane & 15);
        av[m] = *(const short8*)(As + row * 64 + ((slot ^ (row & 7)) << 3));
    }
#pragma unroll
    for (int n = 0; n < 4; ++n) {
        int row = wn * 64 + n * 16 + (lane & 15);
        bv[n] = *(const short8*)(Bs + row * 64 + ((slot ^ (row & 7)) << 3));
    }
}

__device__ __forceinline__ void mfma16(const short8 av[4], const short8 bv[4], f32x4 acc[4][4]) {
    __builtin_amdgcn_s_setprio(1);
#pragma unroll
    for (int m = 0; m < 4; ++m)
#pragma unroll
        for (int n = 0; n < 4; ++n)
            acc[m][n] = __builtin_amdgcn_mfma_f32_16x16x32_bf16(av[m], bv[n], acc[m][n], 0, 0, 0);
    __builtin_amdgcn_s_setprio(0);
}

// ---------------- stage A (r5, kept): Apk[kvi][et][tt][h][img] ----------------
__global__ __launch_bounds__(256, 2)
void k_gemm_A(const ushort_t* __restrict__ Mpk, const ushort_t* __restrict__ xpk,
              ushort_t* __restrict__ Apk, int kvLo) {
    __shared__ ushort_t smem[2][2][8192];
    int bid = blockIdx.x;
    int kvi = bid / 96; int rem = bid % 96; int et = rem / 16, tt = rem % 16;
    int kv = kvLo + kvi;
    const ushort_t* Abase = Mpk + ((size_t)(kv * 6 + et) * 12) * 8192;
    const ushort_t* Bbase = xpk + (size_t)(tt * 12) * 8192;
    int tid = threadIdx.x, lane = tid & 63, wave = tid >> 6;
    int wm = wave >> 1, wn = wave & 1;

    auto stage4 = [&](const ushort_t* src, ushort_t* dst) {
        const char* s = (const char*)src + wave * 4096 + lane * 16;
        char* l = (char*)dst + wave * 4096;
#pragma unroll
        for (int p = 0; p < 4; ++p)
            __builtin_amdgcn_global_load_lds((const glb_u32*)(s + p * 1024),
                                             (lds_u32*)(l + p * 1024), 16, 0, 0);
    };

    f32x4 acc[4][4];
#pragma unroll
    for (int m = 0; m < 4; ++m)
#pragma unroll
        for (int n = 0; n < 4; ++n) acc[m][n] = (f32x4){0.f, 0.f, 0.f, 0.f};

    stage4(Abase, smem[0][0]);
    stage4(Bbase, smem[0][1]);

    for (int s = 0; s < 12; ++s) {
        int c = s & 1;
        bool more = (s + 1 < 12);
        if (more) {
            stage4(Abase + (s + 1) * 8192, smem[c ^ 1][0]);
            asm volatile("s_waitcnt vmcnt(4)" ::: "memory");
        } else {
            asm volatile("s_waitcnt vmcnt(0)" ::: "memory");
        }
        __builtin_amdgcn_s_barrier();
        __builtin_amdgcn_sched_barrier(0);

        const ushort_t* As = smem[c][0];
        const ushort_t* Bs = smem[c][1];
        short8 av0[4], bv0[4], av1[4], bv1[4];
        read_frags(As, Bs, lane, wm, wn, 0, av0, bv0);
        asm volatile("s_waitcnt lgkmcnt(0)" ::: "memory");
        __builtin_amdgcn_sched_barrier(0);
        read_frags(As, Bs, lane, wm, wn, 1, av1, bv1);
        if (more) stage4(Bbase + (s + 1) * 8192, smem[c ^ 1][1]);
        mfma16(av0, bv0, acc);
        asm volatile("s_waitcnt lgkmcnt(0)" ::: "memory");
        __builtin_amdgcn_sched_barrier(0);
        mfma16(av1, bv1, acc);
        __builtin_amdgcn_s_barrier();
    }

    ushort_t* sm = &smem[0][0][0];
#pragma unroll
    for (int m = 0; m < 4; ++m) {
        int rb = wm * 64 + m * 16 + ((lane >> 4) << 2);
#pragma unroll
        for (int n = 0; n < 4; ++n) {
            int cb = wn * 64 + n * 16 + (lane & 15);
            int h = cb >> 6, c6 = cb & 63, sl = c6 >> 3, j = c6 & 7;
#pragma unroll
            for (int r = 0; r < 4; ++r) {
                int row = rb + r;
                sm[h * 8192 + row * 64 + ((sl ^ (row & 7)) << 3) + j] = f2bf(acc[m][n][r]);
            }
        }
    }
    __syncthreads();
    uint4* d4 = (uint4*)(Apk + ((size_t)((kvi * 6 + et) * 16 + tt) * 2) * 8192);
    const uint4* s4 = (const uint4*)sm;
#pragma unroll
    for (int p = 0; p < 8; ++p) d4[p * 256 + tid] = s4[p * 256 + tid];
}

// ---------------- stage B v8: faithful m201 4-phase schedule ----------------
// Per K-tile (4 images A0,A1,B0,B1): 4 phases, phase q = (aq=q>>1, bq=q&1).
// Wave wn's cols = bq*128 + wn*32 (+nf*16): bq selects the B IMAGE, so B1 is
// first consumed at phase 1 -> counted gates vmcnt(2) at q0/q3 ends, never 0.
// Phase: 12 ds_read -> 2 gload (image q of t+1) -> barrier -> lgkm(0) ->
//        16 MFMA -> [gate] -> barrier.
__global__ __launch_bounds__(512, 2)
void k_gemm_Bv8(const ushort_t* __restrict__ Tpk, const ushort_t* __restrict__ Apk,
                float* __restrict__ chunk, int kvLo, int nkv, int accum) {
    __shared__ ushort_t smem[2][4][8192];   // [buf][img: A_top, A_bot, B_e0, B_e1]

    int bid = blockIdx.x;                    // bijective XCD swizzle: 216 = 8*27
    int lid = (bid & 7) * 27 + (bid >> 3);
    int et2 = lid / 72;
    int r = lid % 72;
    int p = 0;
#pragma unroll
    for (int t = 1; t < 8; ++t) if (r >= t * t + t) p = t;
    int jj = r - (p * p + p);

    int tid = threadIdx.x, lane = tid & 63, wave = tid >> 6;
    int wm = wave >> 2, wn = wave & 3;       // 2 x 4 waves
    int l15 = lane & 15;

    int sA = 2 * p - jj + 1;                 // lag slot of top row block (+1 zero-slot bias)
    int e0 = et2 * 2;

    f32x4 acc[8][4];
#pragma unroll
    for (int m = 0; m < 8; ++m)
#pragma unroll
        for (int n = 0; n < 4; ++n) acc[m][n] = (f32x4){0.f, 0.f, 0.f, 0.f};

    auto src_img = [&](int s, int q) -> const ushort_t* {
        int kvz = s >> 1, h = s & 1;
        if (q < 2)
            return Tpk + ((size_t)(((kvLo + kvz) * 17 + sA + q) * 2 + h)) * 8192;
        return Apk + ((size_t)(((kvz * 6 + e0 + (q - 2)) * 16 + jj) * 2 + h)) * 8192;
    };
    auto stage_img = [&](int s, int c, int q) {
        const char* sp = (const char*)src_img(s, q) + wave * 2048 + lane * 16;
        char* lp = (char*)&smem[c][q][0] + wave * 2048;
        __builtin_amdgcn_global_load_lds((const glb_u32*)sp, (lds_u32*)lp, 16, 0, 0);
        __builtin_amdgcn_global_load_lds((const glb_u32*)(sp + 1024), (lds_u32*)(lp + 1024), 16, 0, 0);
    };

    int NS = nkv * 2;
    // prologue: stage all 4 images of tile 0 into buf 0
#pragma unroll
    for (int q = 0; q < 4; ++q) stage_img(0, 0, q);

    for (int s = 0; s < NS; ++s) {
        int c = s & 1;
        bool more = (s + 1 < NS);
        int sn = more ? s + 1 : s;           // dummy re-stage on last tile keeps gates uniform
        const ushort_t* As_w = &smem[c][wm][0];

#pragma unroll
        for (int q = 0; q < 4; ++q) {
            const int aq = q >> 1, bq = q & 1;
            const ushort_t* Bs_w = &smem[c][2 + bq][0];

            // 12 ds_reads for this phase's quadrant (in flight across the barrier)
            short8 av[2][4], bv[2][2];
#pragma unroll
            for (int kk = 0; kk < 2; ++kk) {
                int slot = kk * 4 + (lane >> 4);
#pragma unroll
                for (int m = 0; m < 4; ++m) {
                    int row = aq * 64 + m * 16 + l15;
                    av[kk][m] = *(const short8*)(As_w + row * 64 + ((slot ^ (row & 7)) << 3));
                }
#pragma unroll
                for (int nf = 0; nf < 2; ++nf) {
                    int row = wn * 32 + nf * 16 + l15;
                    bv[kk][nf] = *(const short8*)(Bs_w + row * 64 + ((slot ^ (row & 7)) << 3));
                }
            }
            // stage image q of next tile into the other buffer
            stage_img(sn, c ^ 1, q);

            __builtin_amdgcn_s_barrier();
            asm volatile("s_waitcnt lgkmcnt(0)" ::: "memory");
            __builtin_amdgcn_sched_barrier(0);

            __builtin_amdgcn_s_setprio(1);
#pragma unroll
            for (int kk = 0; kk < 2; ++kk)
#pragma unroll
                for (int m = 0; m < 4; ++m)
#pragma unroll
                    for (int nf = 0; nf < 2; ++nf)
                        acc[aq * 4 + m][bq * 2 + nf] = __builtin_amdgcn_mfma_f32_16x16x32_bf16(
                            av[kk][m], bv[kk][nf], acc[aq * 4 + m][bq * 2 + nf], 0, 0, 0);
            __builtin_amdgcn_s_setprio(0);

            if (q == 0 || q == 3)
                asm volatile("s_waitcnt vmcnt(2)" ::: "memory");  // counted gate, never 0
            __builtin_amdgcn_s_barrier();
        }
    }

    // epilogue: store/accumulate this chunk's 256x256 f32 slab
    // col for acc index n: (n>>1)*128 + wn*32 + (n&1)*16
    float* dst = chunk + (size_t)lid * 65536;
#pragma unroll
    for (int m = 0; m < 8; ++m) {
        int r0 = wm * 128 + m * 16 + ((lane >> 4) << 2);
#pragma unroll
        for (int n = 0; n < 4; ++n) {
            int cc = (n >> 1) * 128 + wn * 32 + (n & 1) * 16 + l15;
#pragma unroll
            for (int rr = 0; rr < 4; ++rr) {
                float* q = dst + (size_t)(r0 + rr) * 256 + cc;
                float v = acc[m][n][rr];
                if (accum) v += *q;
                *q = v;
            }
        }
    }
}

// out[s,e] = sum over jj-chunks of tile (p = s>>8, et2 = e>>8)
__global__ void k_reduce(const float* __restrict__ chunk, float* __restrict__ out, int n4) {
    int idx = blockIdx.x * blockDim.x + threadIdx.x;
    if (idx < n4) {
        int srow = idx / (DDIM / 4);
        int e4 = idx % (DDIM / 4);
        int p = srow >> 8;
        int et2 = e4 >> 6;
        int cb = et2 * 72 + p * p + p;
        int njj = 2 * p + 2;
        const float* base = chunk + (size_t)cb * 65536 + (size_t)(srow & 255) * 256 + (e4 & 63) * 4;
        float4 s = {0.f, 0.f, 0.f, 0.f};
        for (int j = 0; j < njj; ++j) {
            float4 t = *(const float4*)(base + (size_t)j * 65536);
            s.x += t.x; s.y += t.y; s.z += t.z; s.w += t.w;
        }
        ((float4*)out)[idx] = s;
    }
}

extern "C" void kernel_launch(void* const* d_in, const int* in_sizes, int n_in,
                              void* d_out, int out_size, void* d_ws, size_t ws_size,
                              hipStream_t stream) {
    (void)in_sizes; (void)n_in;
    const float* x   = (const float*)d_in[0];
    const float* phi = (const float*)d_in[1];
    const float* Mp  = (const float*)d_in[2];
    const float* Mm  = (const float*)d_in[3];
    float* out = (float*)d_out;

    char* ws = (char*)d_ws;
    size_t off = 0;
    auto alloc = [&](size_t bytes) { size_t o = off; off += (bytes + 255) & ~(size_t)255; return o; };
    size_t o_xpk   = alloc((size_t)16 * 12 * 8192 * 2);
    size_t o_Mpk   = alloc((size_t)NKV * 6 * 12 * 8192 * 2);
    size_t o_Tpk   = alloc((size_t)NKV * 17 * 2 * 8192 * 2);
    size_t o_chunk = alloc((size_t)NCHUNK * 65536 * 4);
    size_t fixed = off;

    int C = 0;
    const int cand[4] = {48, 24, 16, 8};
    for (int ci = 0; ci < 4; ++ci) {
        if (fixed + (size_t)cand[ci] * 6 * 16 * 2 * 8192 * 2 <= ws_size) { C = cand[ci]; break; }
    }
    if (C == 0) {
        hipMemsetAsync(d_out, 0, (size_t)out_size * 4, stream);
        return;
    }
    size_t o_Apk = alloc((size_t)C * 6 * 16 * 2 * 8192 * 2);

    ushort_t* xpk  = (ushort_t*)(ws + o_xpk);
    ushort_t* Mpk  = (ushort_t*)(ws + o_Mpk);
    ushort_t* Tpk  = (ushort_t*)(ws + o_Tpk);
    float*    chnk = (float*)(ws + o_chunk);
    ushort_t* Apk  = (ushort_t*)(ws + o_Apk);

    k_pack_x<<<16 * 12, 256, 0, stream>>>(x, xpk);
    k_pack_M<<<NKV * 6 * 12, 256, 0, stream>>>(Mp, Mm, Mpk);
    k_build_T<<<NKV * 17, 256, 0, stream>>>(phi, Tpk);

    for (int kvLo = 0; kvLo < NKV; kvLo += C) {
        k_gemm_A<<<C * 96, 256, 0, stream>>>(Mpk, xpk, Apk, kvLo);
        k_gemm_Bv8<<<NCHUNK, 512, 0, stream>>>(Tpk, Apk, chnk, kvLo, C, kvLo > 0);
    }
    int n4 = SEQ * DDIM / 4;
    k_reduce<<<(n4 + 255) / 256, 256, 0, stream>>>(chnk, out, n4);
}

// Round 9
// 334.744 us; speedup vs baseline: 1.1706x; 1.1706x over previous
//
#include <hip/hip_runtime.h>
#include <hip/hip_bf16.h>
#include <stdint.h>

#define SEQ 2048
#define DDIM 768
#define KF 24
#define NKV 48
#define NZC 8   // outz split-K slices (jj-chunk of 2)

typedef unsigned short ushort_t;
typedef __attribute__((ext_vector_type(8))) short short8;
typedef __attribute__((ext_vector_type(4))) float f32x4;

typedef __attribute__((address_space(3))) uint32_t lds_u32;
typedef __attribute__((address_space(1))) uint32_t glb_u32;

__device__ __forceinline__ unsigned short f2bf(float f) {
    union { float f; uint32_t u; } v; v.f = f;
    uint32_t u = v.u;
    return (unsigned short)((u + 0x7fff + ((u >> 16) & 1)) >> 16);
}

// Image layout for a [128 rows][64 k] bf16 slab (16 KB), XOR-swizzled:
//   idx(row,k) = row*64 + (((k>>3) ^ (row&7))<<3) + (k&7)

// ---------------- prep: pack x ----------------
__global__ void k_pack_x(const float* __restrict__ x, ushort_t* __restrict__ xpk) {
    int b = blockIdx.x;            // tt*12 + ks
    int tt = b / 12, ks = b % 12;
    int tid = threadIdx.x;
    ushort_t* dst = xpk + (size_t)b * 8192;
    const float* src = x + (size_t)tt * 128 * DDIM + ks * 64;
#pragma unroll
    for (int p = 0; p < 4; ++p) {
        int s = p * 256 + tid;
        int row = s >> 3, sl = s & 7;
        const float* rp = src + (size_t)row * DDIM + sl * 8;
        float4 a = *(const float4*)rp;
        float4 c = *(const float4*)(rp + 4);
        ushort_t v[8] = {f2bf(a.x), f2bf(a.y), f2bf(a.z), f2bf(a.w),
                         f2bf(c.x), f2bf(c.y), f2bf(c.z), f2bf(c.w)};
        *(uint4*)(dst + row * 64 + ((sl ^ (row & 7)) << 3)) = *(uint4*)v;
    }
}

// ---------------- prep: pack M transposed ----------------
__global__ void k_pack_M(const float* __restrict__ Mp, const float* __restrict__ Mm,
                         ushort_t* __restrict__ Mpk) {
    __shared__ ushort_t lt[128 * 66];
    int b = blockIdx.x;            // (kv*6 + et)*12 + ks
    int kv = b / 72; int rem = b % 72; int et = rem / 12, ks = rem % 12;
    const float* src = ((kv < KF) ? Mp + (size_t)kv * DDIM * DDIM
                                  : Mm + (size_t)(kv - KF) * DDIM * DDIM)
                       + (size_t)(ks * 64) * DDIM + et * 128;
    int tid = threadIdx.x;
#pragma unroll
    for (int p = 0; p < 32; ++p) {
        int lin = p * 256 + tid;
        int d = lin >> 7, e = lin & 127;
        lt[e * 66 + d] = f2bf(src[(size_t)d * DDIM + e]);
    }
    __syncthreads();
    ushort_t* dst = Mpk + (size_t)b * 8192;
#pragma unroll
    for (int p = 0; p < 4; ++p) {
        int s = p * 256 + tid; int row = s >> 3, sl = s & 7;
        ushort_t v[8];
#pragma unroll
        for (int j = 0; j < 8; ++j) v[j] = lt[row * 66 + sl * 8 + j];
        *(uint4*)(dst + row * 64 + ((sl ^ (row & 7)) << 3)) = *(uint4*)v;
    }
}

// ---------------- prep: build Toeplitz blocks (16 lag slots) ----------------
__global__ void k_build_T(const float* __restrict__ phi, ushort_t* __restrict__ Tpk) {
    __shared__ float phiL[256];
    int b = blockIdx.x;            // kv*16 + lag
    int kv = b >> 4, dm = b & 15;
    int k = kv % KF; bool neg = kv >= KF;
    int tid = threadIdx.x;
    int tau = 128 * dm - 127 + tid;
    float v = 0.f;
    if (tid < 255 && tau >= 0 && tau < SEQ) {
        v = phi[(size_t)tau * KF + k];
        if (neg && (tau & 1)) v = -v;
    }
    phiL[tid] = v;
    __syncthreads();
    ushort_t* dst = Tpk + (size_t)b * 2 * 8192;
#pragma unroll
    for (int h = 0; h < 2; ++h) {
#pragma unroll
        for (int p = 0; p < 4; ++p) {
            int s = p * 256 + tid; int row = s >> 3, sl = s & 7;
            ushort_t v8[8];
#pragma unroll
            for (int j = 0; j < 8; ++j) {
                int col = h * 64 + sl * 8 + j;
                v8[j] = f2bf(phiL[row - col + 127]);
            }
            *(uint4*)(dst + h * 8192 + row * 64 + ((sl ^ (row & 7)) << 3)) = *(uint4*)v8;
        }
    }
}

// ---------------- shared fragment-read helpers ----------------

__device__ __forceinline__ void read_frags(const ushort_t* As, const ushort_t* Bs,
                                           int lane, int wm, int wn, int kk,
                                           short8 av[4], short8 bv[4]) {
    int slot = kk * 4 + (lane >> 4);
#pragma unroll
    for (int m = 0; m < 4; ++m) {
        int row = wm * 64 + m * 16 + (lane & 15);
        av[m] = *(const short8*)(As + row * 64 + ((slot ^ (row & 7)) << 3));
    }
#pragma unroll
    for (int n = 0; n < 4; ++n) {
        int row = wn * 64 + n * 16 + (lane & 15);
        bv[n] = *(const short8*)(Bs + row * 64 + ((slot ^ (row & 7)) << 3));
    }
}

__device__ __forceinline__ void mfma16(const short8 av[4], const short8 bv[4], f32x4 acc[4][4]) {
    __builtin_amdgcn_s_setprio(1);
#pragma unroll
    for (int m = 0; m < 4; ++m)
#pragma unroll
        for (int n = 0; n < 4; ++n)
            acc[m][n] = __builtin_amdgcn_mfma_f32_16x16x32_bf16(av[m], bv[n], acc[m][n], 0, 0, 0);
    __builtin_amdgcn_s_setprio(0);
}

// ---------------- stage A (r5 pipelined): Apk[kv][et][tt][h][img] ----------------
__global__ __launch_bounds__(256, 2)
void k_gemm_A(const ushort_t* __restrict__ Mpk, const ushort_t* __restrict__ xpk,
              ushort_t* __restrict__ Apk) {
    __shared__ ushort_t smem[2][2][8192];
    int bid = blockIdx.x;
    int kv = bid / 96; int rem = bid % 96; int et = rem / 16, tt = rem % 16;
    const ushort_t* Abase = Mpk + ((size_t)(kv * 6 + et) * 12) * 8192;
    const ushort_t* Bbase = xpk + (size_t)(tt * 12) * 8192;
    int tid = threadIdx.x, lane = tid & 63, wave = tid >> 6;
    int wm = wave >> 1, wn = wave & 1;

    auto stage4 = [&](const ushort_t* src, ushort_t* dst) {
        const char* s = (const char*)src + wave * 4096 + lane * 16;
        char* l = (char*)dst + wave * 4096;
#pragma unroll
        for (int p = 0; p < 4; ++p)
            __builtin_amdgcn_global_load_lds((const glb_u32*)(s + p * 1024),
                                             (lds_u32*)(l + p * 1024), 16, 0, 0);
    };

    f32x4 acc[4][4];
#pragma unroll
    for (int m = 0; m < 4; ++m)
#pragma unroll
        for (int n = 0; n < 4; ++n) acc[m][n] = (f32x4){0.f, 0.f, 0.f, 0.f};

    stage4(Abase, smem[0][0]);
    stage4(Bbase, smem[0][1]);

    for (int s = 0; s < 12; ++s) {
        int c = s & 1;
        bool more = (s + 1 < 12);
        if (more) {
            stage4(Abase + (s + 1) * 8192, smem[c ^ 1][0]);
            asm volatile("s_waitcnt vmcnt(4)" ::: "memory");
        } else {
            asm volatile("s_waitcnt vmcnt(0)" ::: "memory");
        }
        __builtin_amdgcn_s_barrier();
        __builtin_amdgcn_sched_barrier(0);

        const ushort_t* As = smem[c][0];
        const ushort_t* Bs = smem[c][1];
        short8 av0[4], bv0[4], av1[4], bv1[4];
        read_frags(As, Bs, lane, wm, wn, 0, av0, bv0);
        asm volatile("s_waitcnt lgkmcnt(0)" ::: "memory");
        __builtin_amdgcn_sched_barrier(0);
        read_frags(As, Bs, lane, wm, wn, 1, av1, bv1);
        if (more) stage4(Bbase + (s + 1) * 8192, smem[c ^ 1][1]);
        mfma16(av0, bv0, acc);
        asm volatile("s_waitcnt lgkmcnt(0)" ::: "memory");
        __builtin_amdgcn_sched_barrier(0);
        mfma16(av1, bv1, acc);
        __builtin_amdgcn_s_barrier();
    }

    ushort_t* sm = &smem[0][0][0];
#pragma unroll
    for (int m = 0; m < 4; ++m) {
        int rb = wm * 64 + m * 16 + ((lane >> 4) << 2);
#pragma unroll
        for (int n = 0; n < 4; ++n) {
            int cb = wn * 64 + n * 16 + (lane & 15);
            int h = cb >> 6, c6 = cb & 63, sl = c6 >> 3, j = c6 & 7;
#pragma unroll
            for (int r = 0; r < 4; ++r) {
                int row = rb + r;
                sm[h * 8192 + row * 64 + ((sl ^ (row & 7)) << 3) + j] = f2bf(acc[m][n][r]);
            }
        }
    }
    __syncthreads();
    uint4* d4 = (uint4*)(Apk + ((size_t)((kv * 6 + et) * 16 + tt) * 2) * 8192);
    const uint4* s4 = (const uint4*)sm;
#pragma unroll
    for (int p = 0; p < 8; ++p) d4[p * 256 + tid] = s4[p * 256 + tid];
}

// ---------------- stage B (v4 body, single pass, pure store) ----------------
// Work unit: (i1, et, zc) with jj in [2*zc, min(2*zc+1, i1)], kv over all 48.
// Grid = 6 et * 72 chunks = 432 blocks, 64 KB LDS -> 2 blocks/CU.
__global__ __launch_bounds__(256, 2)
void k_gemm_Bv4(const ushort_t* __restrict__ Tpk, const ushort_t* __restrict__ Apk,
                float* __restrict__ outz) {
    __shared__ ushort_t smem[2][2][8192];   // [buf][0=T, 1=A]

    int bid = blockIdx.x;                    // bijective XCD swizzle: 432 = 8*54
    int lid = (bid & 7) * 54 + (bid >> 3);
    int et = lid / 72;
    int cidx = lid % 72;
    int i1 = 0, zc = 0, base = 0;
#pragma unroll
    for (int t = 0; t < 16; ++t) {           // heaviest i1 first
        int cand = 15 - t;
        int nc = (cand >> 1) + 1;
        if (cidx < base + nc) { i1 = cand; zc = cidx - base; break; }
        base += nc;
    }
    int jlo = zc * 2;
    int jhi = (jlo + 1 < i1) ? (jlo + 1) : i1;
    int NS = NKV * (jhi - jlo + 1) * 2;

    int tid = threadIdx.x, lane = tid & 63, wave = tid >> 6;
    int wm = wave >> 1, wn = wave & 1;

    f32x4 acc[4][4];
#pragma unroll
    for (int m = 0; m < 4; ++m)
#pragma unroll
        for (int n = 0; n < 4; ++n) acc[m][n] = (f32x4){0.f, 0.f, 0.f, 0.f};

    auto timg = [&](int kv, int jj, int h) -> const ushort_t* {
        return Tpk + ((size_t)((kv * 16 + (i1 - jj)) * 2 + h)) * 8192;
    };
    auto aimg = [&](int kv, int jj, int h) -> const ushort_t* {
        return Apk + ((size_t)(((kv * 6 + et) * 16 + jj) * 2 + h)) * 8192;
    };
    auto stage4 = [&](const ushort_t* src, ushort_t* dst) {
        const char* s = (const char*)src + wave * 4096 + lane * 16;
        char* l = (char*)dst + wave * 4096;
#pragma unroll
        for (int p = 0; p < 4; ++p)
            __builtin_amdgcn_global_load_lds((const glb_u32*)(s + p * 1024),
                                             (lds_u32*)(l + p * 1024), 16, 0, 0);
    };

    int kv = 0, jj = jlo, h = 0;
    stage4(timg(kv, jj, h), smem[0][0]);
    stage4(aimg(kv, jj, h), smem[0][1]);

    for (int s = 0; s < NS; ++s) {
        int c = s & 1;
        int nh = h ^ 1, njj = jj, nkvv = kv;
        if (!nh) { njj = jj + 1; if (njj > jhi) { njj = jlo; nkvv = kv + 1; } }
        bool more = (s + 1 < NS);

        if (more) {
            stage4(timg(nkvv, njj, nh), smem[c ^ 1][0]);
            asm volatile("s_waitcnt vmcnt(4)" ::: "memory");   // this step's 8 landed
        } else {
            asm volatile("s_waitcnt vmcnt(0)" ::: "memory");
        }
        __builtin_amdgcn_s_barrier();
        __builtin_amdgcn_sched_barrier(0);

        const ushort_t* As = smem[c][0];
        const ushort_t* Bs = smem[c][1];
        short8 av[2][4], bv[2][4];
#pragma unroll
        for (int kk = 0; kk < 2; ++kk) {
            int slot = kk * 4 + (lane >> 4);
#pragma unroll
            for (int m = 0; m < 4; ++m) {
                int row = wm * 64 + m * 16 + (lane & 15);
                av[kk][m] = *(const short8*)(As + row * 64 + ((slot ^ (row & 7)) << 3));
            }
#pragma unroll
            for (int n = 0; n < 4; ++n) {
                int row = wn * 64 + n * 16 + (lane & 15);
                bv[kk][n] = *(const short8*)(Bs + row * 64 + ((slot ^ (row & 7)) << 3));
            }
        }
        if (more) stage4(aimg(nkvv, njj, nh), smem[c ^ 1][1]);

        asm volatile("s_waitcnt lgkmcnt(0)" ::: "memory");
        __builtin_amdgcn_sched_barrier(0);

        __builtin_amdgcn_s_setprio(1);
#pragma unroll
        for (int kk = 0; kk < 2; ++kk)
#pragma unroll
            for (int m = 0; m < 4; ++m)
#pragma unroll
                for (int n = 0; n < 4; ++n)
                    acc[m][n] = __builtin_amdgcn_mfma_f32_16x16x32_bf16(av[kk][m], bv[kk][n], acc[m][n], 0, 0, 0);
        __builtin_amdgcn_s_setprio(0);
        __builtin_amdgcn_s_barrier();
        kv = nkvv; jj = njj; h = nh;
    }

    float* dst = outz + ((size_t)zc * SEQ + (size_t)i1 * 128) * DDIM + et * 128;
#pragma unroll
    for (int m = 0; m < 4; ++m) {
        int rb = wm * 64 + m * 16 + ((lane >> 4) << 2);
#pragma unroll
        for (int n = 0; n < 4; ++n) {
            int cb = wn * 64 + n * 16 + (lane & 15);
#pragma unroll
            for (int r = 0; r < 4; ++r)
                dst[(size_t)(rb + r) * DDIM + cb] = acc[m][n][r];
        }
    }
}

// sum only z-slices that were written for this row: zc <= (srow>>7)/2
__global__ void k_reduce(const float* __restrict__ outz, float* __restrict__ out, int n4) {
    int idx = blockIdx.x * blockDim.x + threadIdx.x;
    if (idx < n4) {
        int srow = idx / (DDIM / 4);
        int zmax = srow >> 8;
        if (zmax > NZC - 1) zmax = NZC - 1;
        float4 s = ((const float4*)outz)[idx];
        for (int z = 1; z <= zmax; ++z) {
            float4 t = ((const float4*)(outz + (size_t)z * SEQ * DDIM))[idx];
            s.x += t.x; s.y += t.y; s.z += t.z; s.w += t.w;
        }
        ((float4*)out)[idx] = s;
    }
}

extern "C" void kernel_launch(void* const* d_in, const int* in_sizes, int n_in,
                              void* d_out, int out_size, void* d_ws, size_t ws_size,
                              hipStream_t stream) {
    (void)in_sizes; (void)n_in;
    const float* x   = (const float*)d_in[0];
    const float* phi = (const float*)d_in[1];
    const float* Mp  = (const float*)d_in[2];
    const float* Mm  = (const float*)d_in[3];
    float* out = (float*)d_out;

    char* ws = (char*)d_ws;
    size_t off = 0;
    auto alloc = [&](size_t bytes) { size_t o = off; off += (bytes + 255) & ~(size_t)255; return o; };
    size_t o_xpk = alloc((size_t)16 * 12 * 8192 * 2);                // 3.0 MB
    size_t o_Mpk = alloc((size_t)NKV * 6 * 12 * 8192 * 2);           // 56.6 MB (aliased by outz later)
    size_t o_Tpk = alloc((size_t)NKV * 16 * 2 * 8192 * 2);           // 25.2 MB
    size_t o_Apk = alloc((size_t)NKV * 6 * 16 * 2 * 8192 * 2);       // 151.0 MB
    if (off > ws_size) {   // should never happen (236 MB total)
        hipMemsetAsync(d_out, 0, (size_t)out_size * 4, stream);
        return;
    }

    ushort_t* xpk = (ushort_t*)(ws + o_xpk);
    ushort_t* Mpk = (ushort_t*)(ws + o_Mpk);
    ushort_t* Tpk = (ushort_t*)(ws + o_Tpk);
    ushort_t* Apk = (ushort_t*)(ws + o_Apk);
    float*   outz = (float*)(ws + o_Mpk);   // alias: Mpk dead after gemm_A; 50.3 <= 56.6 MB

    k_pack_x<<<16 * 12, 256, 0, stream>>>(x, xpk);
    k_pack_M<<<NKV * 6 * 12, 256, 0, stream>>>(Mp, Mm, Mpk);
    k_build_T<<<NKV * 16, 256, 0, stream>>>(phi, Tpk);
    k_gemm_A<<<NKV * 96, 256, 0, stream>>>(Mpk, xpk, Apk);
    k_gemm_Bv4<<<432, 256, 0, stream>>>(Tpk, Apk, outz);
    int n4 = SEQ * DDIM / 4;
    k_reduce<<<(n4 + 255) / 256, 256, 0, stream>>>(outz, out, n4);
}

// Round 10
// 328.197 us; speedup vs baseline: 1.1940x; 1.0199x over previous
//
#include <hip/hip_runtime.h>
#include <hip/hip_bf16.h>
#include <stdint.h>

#define SEQ 2048
#define DDIM 768
#define KF 24
#define NKV 48
#define NZC 8   // outz split-K slices (jj-chunk of 2)

typedef unsigned short ushort_t;
typedef __attribute__((ext_vector_type(8))) short short8;
typedef __attribute__((ext_vector_type(4))) float f32x4;

typedef __attribute__((address_space(3))) uint32_t lds_u32;
typedef __attribute__((address_space(1))) uint32_t glb_u32;

__device__ __forceinline__ unsigned short f2bf(float f) {
    union { float f; uint32_t u; } v; v.f = f;
    uint32_t u = v.u;
    return (unsigned short)((u + 0x7fff + ((u >> 16) & 1)) >> 16);
}

// Image layout for a [128 rows][64 k] bf16 slab (16 KB), XOR-swizzled:
//   idx(row,k) = row*64 + (((k>>3) ^ (row&7))<<3) + (k&7)

// ---------------- prep: pack x ----------------
__global__ void k_pack_x(const float* __restrict__ x, ushort_t* __restrict__ xpk) {
    int b = blockIdx.x;            // tt*12 + ks
    int tt = b / 12, ks = b % 12;
    int tid = threadIdx.x;
    ushort_t* dst = xpk + (size_t)b * 8192;
    const float* src = x + (size_t)tt * 128 * DDIM + ks * 64;
#pragma unroll
    for (int p = 0; p < 4; ++p) {
        int s = p * 256 + tid;
        int row = s >> 3, sl = s & 7;
        const float* rp = src + (size_t)row * DDIM + sl * 8;
        float4 a = *(const float4*)rp;
        float4 c = *(const float4*)(rp + 4);
        ushort_t v[8] = {f2bf(a.x), f2bf(a.y), f2bf(a.z), f2bf(a.w),
                         f2bf(c.x), f2bf(c.y), f2bf(c.z), f2bf(c.w)};
        *(uint4*)(dst + row * 64 + ((sl ^ (row & 7)) << 3)) = *(uint4*)v;
    }
}

// ---------------- prep: pack M transposed ----------------
__global__ void k_pack_M(const float* __restrict__ Mp, const float* __restrict__ Mm,
                         ushort_t* __restrict__ Mpk) {
    __shared__ ushort_t lt[128 * 66];
    int b = blockIdx.x;            // (kv*6 + et)*12 + ks
    int kv = b / 72; int rem = b % 72; int et = rem / 12, ks = rem % 12;
    const float* src = ((kv < KF) ? Mp + (size_t)kv * DDIM * DDIM
                                  : Mm + (size_t)(kv - KF) * DDIM * DDIM)
                       + (size_t)(ks * 64) * DDIM + et * 128;
    int tid = threadIdx.x;
#pragma unroll
    for (int p = 0; p < 32; ++p) {
        int lin = p * 256 + tid;
        int d = lin >> 7, e = lin & 127;
        lt[e * 66 + d] = f2bf(src[(size_t)d * DDIM + e]);
    }
    __syncthreads();
    ushort_t* dst = Mpk + (size_t)b * 8192;
#pragma unroll
    for (int p = 0; p < 4; ++p) {
        int s = p * 256 + tid; int row = s >> 3, sl = s & 7;
        ushort_t v[8];
#pragma unroll
        for (int j = 0; j < 8; ++j) v[j] = lt[row * 66 + sl * 8 + j];
        *(uint4*)(dst + row * 64 + ((sl ^ (row & 7)) << 3)) = *(uint4*)v;
    }
}

// ---------------- prep: build Toeplitz blocks (17 lag slots, slot 0 = zeros) ----------------
__global__ void k_build_T(const float* __restrict__ phi, ushort_t* __restrict__ Tpk) {
    __shared__ float phiL[256];
    int b = blockIdx.x;            // kv*17 + slot
    int kv = b / 17, slot = b % 17;
    int dm = slot - 1;             // lag block; dm = -1 -> all zeros
    int k = kv % KF; bool neg = kv >= KF;
    int tid = threadIdx.x;
    int tau = 128 * dm - 127 + tid;
    float v = 0.f;
    if (tid < 255 && tau >= 0 && tau < SEQ) {
        v = phi[(size_t)tau * KF + k];
        if (neg && (tau & 1)) v = -v;
    }
    phiL[tid] = v;
    __syncthreads();
    ushort_t* dst = Tpk + (size_t)b * 2 * 8192;
#pragma unroll
    for (int h = 0; h < 2; ++h) {
#pragma unroll
        for (int p = 0; p < 4; ++p) {
            int s = p * 256 + tid; int row = s >> 3, sl = s & 7;
            ushort_t v8[8];
#pragma unroll
            for (int j = 0; j < 8; ++j) {
                int col = h * 64 + sl * 8 + j;
                v8[j] = f2bf(phiL[row - col + 127]);
            }
            *(uint4*)(dst + h * 8192 + row * 64 + ((sl ^ (row & 7)) << 3)) = *(uint4*)v8;
        }
    }
}

// ---------------- shared fragment-read helpers ----------------

__device__ __forceinline__ void read_frags(const ushort_t* As, const ushort_t* Bs,
                                           int lane, int wm, int wn, int kk,
                                           short8 av[4], short8 bv[4]) {
    int slot = kk * 4 + (lane >> 4);
#pragma unroll
    for (int m = 0; m < 4; ++m) {
        int row = wm * 64 + m * 16 + (lane & 15);
        av[m] = *(const short8*)(As + row * 64 + ((slot ^ (row & 7)) << 3));
    }
#pragma unroll
    for (int n = 0; n < 4; ++n) {
        int row = wn * 64 + n * 16 + (lane & 15);
        bv[n] = *(const short8*)(Bs + row * 64 + ((slot ^ (row & 7)) << 3));
    }
}

__device__ __forceinline__ void mfma16(const short8 av[4], const short8 bv[4], f32x4 acc[4][4]) {
    __builtin_amdgcn_s_setprio(1);
#pragma unroll
    for (int m = 0; m < 4; ++m)
#pragma unroll
        for (int n = 0; n < 4; ++n)
            acc[m][n] = __builtin_amdgcn_mfma_f32_16x16x32_bf16(av[m], bv[n], acc[m][n], 0, 0, 0);
    __builtin_amdgcn_s_setprio(0);
}

// ---------------- stage A (r5 pipelined): Apk[kv][et][tt][h][img] ----------------
__global__ __launch_bounds__(256, 2)
void k_gemm_A(const ushort_t* __restrict__ Mpk, const ushort_t* __restrict__ xpk,
              ushort_t* __restrict__ Apk) {
    __shared__ ushort_t smem[2][2][8192];
    int bid = blockIdx.x;
    int kv = bid / 96; int rem = bid % 96; int et = rem / 16, tt = rem % 16;
    const ushort_t* Abase = Mpk + ((size_t)(kv * 6 + et) * 12) * 8192;
    const ushort_t* Bbase = xpk + (size_t)(tt * 12) * 8192;
    int tid = threadIdx.x, lane = tid & 63, wave = tid >> 6;
    int wm = wave >> 1, wn = wave & 1;

    auto stage4 = [&](const ushort_t* src, ushort_t* dst) {
        const char* s = (const char*)src + wave * 4096 + lane * 16;
        char* l = (char*)dst + wave * 4096;
#pragma unroll
        for (int p = 0; p < 4; ++p)
            __builtin_amdgcn_global_load_lds((const glb_u32*)(s + p * 1024),
                                             (lds_u32*)(l + p * 1024), 16, 0, 0);
    };

    f32x4 acc[4][4];
#pragma unroll
    for (int m = 0; m < 4; ++m)
#pragma unroll
        for (int n = 0; n < 4; ++n) acc[m][n] = (f32x4){0.f, 0.f, 0.f, 0.f};

    stage4(Abase, smem[0][0]);
    stage4(Bbase, smem[0][1]);

    for (int s = 0; s < 12; ++s) {
        int c = s & 1;
        bool more = (s + 1 < 12);
        if (more) {
            stage4(Abase + (s + 1) * 8192, smem[c ^ 1][0]);
            asm volatile("s_waitcnt vmcnt(4)" ::: "memory");
        } else {
            asm volatile("s_waitcnt vmcnt(0)" ::: "memory");
        }
        __builtin_amdgcn_s_barrier();
        __builtin_amdgcn_sched_barrier(0);

        const ushort_t* As = smem[c][0];
        const ushort_t* Bs = smem[c][1];
        short8 av0[4], bv0[4], av1[4], bv1[4];
        read_frags(As, Bs, lane, wm, wn, 0, av0, bv0);
        asm volatile("s_waitcnt lgkmcnt(0)" ::: "memory");
        __builtin_amdgcn_sched_barrier(0);
        read_frags(As, Bs, lane, wm, wn, 1, av1, bv1);
        if (more) stage4(Bbase + (s + 1) * 8192, smem[c ^ 1][1]);
        mfma16(av0, bv0, acc);
        asm volatile("s_waitcnt lgkmcnt(0)" ::: "memory");
        __builtin_amdgcn_sched_barrier(0);
        mfma16(av1, bv1, acc);
        __builtin_amdgcn_s_barrier();
    }

    ushort_t* sm = &smem[0][0][0];
#pragma unroll
    for (int m = 0; m < 4; ++m) {
        int rb = wm * 64 + m * 16 + ((lane >> 4) << 2);
#pragma unroll
        for (int n = 0; n < 4; ++n) {
            int cb = wn * 64 + n * 16 + (lane & 15);
            int h = cb >> 6, c6 = cb & 63, sl = c6 >> 3, j = c6 & 7;
#pragma unroll
            for (int r = 0; r < 4; ++r) {
                int row = rb + r;
                sm[h * 8192 + row * 64 + ((sl ^ (row & 7)) << 3) + j] = f2bf(acc[m][n][r]);
            }
        }
    }
    __syncthreads();
    uint4* d4 = (uint4*)(Apk + ((size_t)((kv * 6 + et) * 16 + tt) * 2) * 8192);
    const uint4* s4 = (const uint4*)sm;
#pragma unroll
    for (int p = 0; p < 8; ++p) d4[p * 256 + tid] = s4[p * 256 + tid];
}

// ---------------- stage B (v4 body, uniform njj=2 via zero-slot padding) ----------------
// Work unit: (i1, et, zc), jj in {2zc, 2zc+1}; jj > i1 maps to T zero-slot (no-op).
// All 432 blocks identical NS = 192 -> kv-lockstep + no tail variance.
__global__ __launch_bounds__(256, 2)
void k_gemm_Bv4(const ushort_t* __restrict__ Tpk, const ushort_t* __restrict__ Apk,
                float* __restrict__ outz) {
    __shared__ ushort_t smem[2][2][8192];   // [buf][0=T, 1=A]

    int bid = blockIdx.x;                    // bijective XCD swizzle: 432 = 8*54
    int lid = (bid & 7) * 54 + (bid >> 3);
    int et = lid / 72;
    int cidx = lid % 72;
    int i1 = 0, zc = 0, base = 0;
#pragma unroll
    for (int t = 0; t < 16; ++t) {
        int cand = 15 - t;
        int nc = (cand >> 1) + 1;
        if (cidx < base + nc) { i1 = cand; zc = cidx - base; break; }
        base += nc;
    }
    int jlo = zc * 2;
    const int NS = NKV * 2 * 2;              // 48 kv * 2 jj * 2 halves, uniform

    int tid = threadIdx.x, lane = tid & 63, wave = tid >> 6;
    int wm = wave >> 1, wn = wave & 1;

    f32x4 acc[4][4];
#pragma unroll
    for (int m = 0; m < 4; ++m)
#pragma unroll
        for (int n = 0; n < 4; ++n) acc[m][n] = (f32x4){0.f, 0.f, 0.f, 0.f};

    // T slot for (i1, jj): i1 - jj + 1; jj = i1+1 (padding) -> slot 0 = zeros
    auto timg = [&](int kv, int jj, int h) -> const ushort_t* {
        return Tpk + ((size_t)((kv * 17 + (i1 - jj + 1)) * 2 + h)) * 8192;
    };
    auto aimg = [&](int kv, int jj, int h) -> const ushort_t* {
        return Apk + ((size_t)(((kv * 6 + et) * 16 + jj) * 2 + h)) * 8192;
    };
    auto stage4 = [&](const ushort_t* src, ushort_t* dst) {
        const char* s = (const char*)src + wave * 4096 + lane * 16;
        char* l = (char*)dst + wave * 4096;
#pragma unroll
        for (int p = 0; p < 4; ++p)
            __builtin_amdgcn_global_load_lds((const glb_u32*)(s + p * 1024),
                                             (lds_u32*)(l + p * 1024), 16, 0, 0);
    };

    int kv = 0, jj = jlo, h = 0;
    stage4(timg(kv, jj, h), smem[0][0]);
    stage4(aimg(kv, jj, h), smem[0][1]);

    for (int s = 0; s < NS; ++s) {
        int c = s & 1;
        int nh = h ^ 1, njj = jj, nkvv = kv;
        if (!nh) { njj = jj + 1; if (njj > jlo + 1) { njj = jlo; nkvv = kv + 1; } }
        bool more = (s + 1 < NS);

        if (more) {
            stage4(timg(nkvv, njj, nh), smem[c ^ 1][0]);
            asm volatile("s_waitcnt vmcnt(4)" ::: "memory");   // this step's 8 landed
        } else {
            asm volatile("s_waitcnt vmcnt(0)" ::: "memory");
        }
        __builtin_amdgcn_s_barrier();
        __builtin_amdgcn_sched_barrier(0);

        const ushort_t* As = smem[c][0];
        const ushort_t* Bs = smem[c][1];
        short8 av[2][4], bv[2][4];
#pragma unroll
        for (int kk = 0; kk < 2; ++kk) {
            int slot = kk * 4 + (lane >> 4);
#pragma unroll
            for (int m = 0; m < 4; ++m) {
                int row = wm * 64 + m * 16 + (lane & 15);
                av[kk][m] = *(const short8*)(As + row * 64 + ((slot ^ (row & 7)) << 3));
            }
#pragma unroll
            for (int n = 0; n < 4; ++n) {
                int row = wn * 64 + n * 16 + (lane & 15);
                bv[kk][n] = *(const short8*)(Bs + row * 64 + ((slot ^ (row & 7)) << 3));
            }
        }
        if (more) stage4(aimg(nkvv, njj, nh), smem[c ^ 1][1]);

        asm volatile("s_waitcnt lgkmcnt(0)" ::: "memory");
        __builtin_amdgcn_sched_barrier(0);

        __builtin_amdgcn_s_setprio(1);
#pragma unroll
        for (int kk = 0; kk < 2; ++kk)
#pragma unroll
            for (int m = 0; m < 4; ++m)
#pragma unroll
                for (int n = 0; n < 4; ++n)
                    acc[m][n] = __builtin_amdgcn_mfma_f32_16x16x32_bf16(av[kk][m], bv[kk][n], acc[m][n], 0, 0, 0);
        __builtin_amdgcn_s_setprio(0);
        __builtin_amdgcn_s_barrier();
        kv = nkvv; jj = njj; h = nh;
    }

    float* dst = outz + ((size_t)zc * SEQ + (size_t)i1 * 128) * DDIM + et * 128;
#pragma unroll
    for (int m = 0; m < 4; ++m) {
        int rb = wm * 64 + m * 16 + ((lane >> 4) << 2);
#pragma unroll
        for (int n = 0; n < 4; ++n) {
            int cb = wn * 64 + n * 16 + (lane & 15);
#pragma unroll
            for (int r = 0; r < 4; ++r)
                dst[(size_t)(rb + r) * DDIM + cb] = acc[m][n][r];
        }
    }
}

// sum only z-slices that were written for this row: zc <= srow>>8
__global__ void k_reduce(const float* __restrict__ outz, float* __restrict__ out, int n4) {
    int idx = blockIdx.x * blockDim.x + threadIdx.x;
    if (idx < n4) {
        int srow = idx / (DDIM / 4);
        int zmax = srow >> 8;
        if (zmax > NZC - 1) zmax = NZC - 1;
        float4 s = ((const float4*)outz)[idx];
        for (int z = 1; z <= zmax; ++z) {
            float4 t = ((const float4*)(outz + (size_t)z * SEQ * DDIM))[idx];
            s.x += t.x; s.y += t.y; s.z += t.z; s.w += t.w;
        }
        ((float4*)out)[idx] = s;
    }
}

extern "C" void kernel_launch(void* const* d_in, const int* in_sizes, int n_in,
                              void* d_out, int out_size, void* d_ws, size_t ws_size,
                              hipStream_t stream) {
    (void)in_sizes; (void)n_in;
    const float* x   = (const float*)d_in[0];
    const float* phi = (const float*)d_in[1];
    const float* Mp  = (const float*)d_in[2];
    const float* Mm  = (const float*)d_in[3];
    float* out = (float*)d_out;

    char* ws = (char*)d_ws;
    size_t off = 0;
    auto alloc = [&](size_t bytes) { size_t o = off; off += (bytes + 255) & ~(size_t)255; return o; };
    size_t o_xpk = alloc((size_t)16 * 12 * 8192 * 2);                // 3.0 MB
    size_t o_Mpk = alloc((size_t)NKV * 6 * 12 * 8192 * 2);           // 56.6 MB (aliased by outz)
    size_t o_Tpk = alloc((size_t)NKV * 17 * 2 * 8192 * 2);           // 26.8 MB
    size_t o_Apk = alloc((size_t)NKV * 6 * 16 * 2 * 8192 * 2);       // 151.0 MB
    if (off > ws_size) {   // should never happen (~237 MB total; r9 proved >=236 fits)
        hipMemsetAsync(d_out, 0, (size_t)out_size * 4, stream);
        return;
    }

    ushort_t* xpk = (ushort_t*)(ws + o_xpk);
    ushort_t* Mpk = (ushort_t*)(ws + o_Mpk);
    ushort_t* Tpk = (ushort_t*)(ws + o_Tpk);
    ushort_t* Apk = (ushort_t*)(ws + o_Apk);
    float*   outz = (float*)(ws + o_Mpk);   // alias: Mpk dead after gemm_A; 50.3 <= 56.6 MB

    k_pack_x<<<16 * 12, 256, 0, stream>>>(x, xpk);
    k_pack_M<<<NKV * 6 * 12, 256, 0, stream>>>(Mp, Mm, Mpk);
    k_build_T<<<NKV * 17, 256, 0, stream>>>(phi, Tpk);
    k_gemm_A<<<NKV * 96, 256, 0, stream>>>(Mpk, xpk, Apk);
    k_gemm_Bv4<<<432, 256, 0, stream>>>(Tpk, Apk, outz);
    int n4 = SEQ * DDIM / 4;
    k_reduce<<<(n4 + 255) / 256, 256, 0, stream>>>(outz, out, n4);
}